// Round 1
// baseline (1499.424 us; speedup 1.0000x reference)
//
#include <hip/hip_runtime.h>
#include <hip/hip_bf16.h>
#include <math.h>

// Problem constants
#define NB 8
#define NC 64
#define NS 64
#define NPIX 4096      // NS*NS
#define NSEG 256
#define DIM 256
#define DEPTH 4
#define HEADS 8
#define DHD 64
#define MLPD 1024
#define NCLS 4
#define D2 512
#define INNER 512
#define NTOK 2048      // NB*NSEG

// ---------------------------------------------------------------------------
// Patch embedding: x0[b,seg,d] = b_patch[d] + sum_{p: sp[b,p]==seg} sum_c feat2[b,c,p]*Wp[(c*4096+p)*256+d]
// ---------------------------------------------------------------------------

__global__ __launch_bounds__(256) void k_init_x0(float* __restrict__ x0,
                                                 const float* __restrict__ bp) {
    int idx = blockIdx.x * 256 + threadIdx.x;   // 524288 total
    x0[idx] = bp[idx & (DIM - 1)];
}

#define PPB 16
__global__ __launch_bounds__(256) void k_patch(const float* __restrict__ feature,
                                               const int* __restrict__ sp,
                                               const float* __restrict__ Wp,
                                               float* __restrict__ x0) {
    __shared__ float f[NB][NC][PPB];   // 32 KB
    __shared__ int seg[NB][PPB];
    const int p0 = blockIdx.x * PPB;
    const int t = threadIdx.x;
    const float* feat2 = feature + (size_t)2 * NB * NC * NPIX;

    // cooperative load of feat2[b,c,p0..p0+15]: lanes 0..15 -> consecutive pixels (64B lines)
    const int pl = t & (PPB - 1);
    const int pair0 = t >> 4;                 // 0..15
    #pragma unroll
    for (int pass = 0; pass < 32; ++pass) {
        int pair = pass * 16 + pair0;         // 0..511  == b*64 + c
        int b = pair >> 6, c = pair & 63;
        f[b][c][pl] = feat2[((size_t)(b * NC + c)) * NPIX + p0 + pl];
    }
    if (t < NB * PPB) {
        int b = t >> 4;
        seg[b][t & 15] = sp[b * NPIX + p0 + (t & 15)];
    }
    __syncthreads();

    const int d = t;   // 0..255
    for (int q = 0; q < PPB; ++q) {
        float acc[NB];
        #pragma unroll
        for (int b = 0; b < NB; ++b) acc[b] = 0.f;
        const float* wcol = Wp + (size_t)(p0 + q) * DIM + d;
        #pragma unroll 4
        for (int c = 0; c < NC; ++c) {
            float w = wcol[(size_t)c * NPIX * DIM];   // 1KB coalesced per (c,q)
            #pragma unroll
            for (int b = 0; b < NB; ++b) acc[b] = fmaf(f[b][c][q], w, acc[b]);
        }
        #pragma unroll
        for (int b = 0; b < NB; ++b)
            atomicAdd(&x0[((b * NSEG) + seg[b][q]) * DIM + d], acc[b]);
    }
}

// g[b,d] = max_seg x0 ; x[b,seg,0:256]=g, x[b,seg,256:512]=x0
__global__ __launch_bounds__(256) void k_concat(const float* __restrict__ x0,
                                                float* __restrict__ x) {
    const int b = blockIdx.x, part = blockIdx.y;
    const int d = threadIdx.x;
    const float* xb = x0 + (size_t)b * NSEG * DIM;
    float g = -INFINITY;
    for (int s = 0; s < NSEG; ++s) g = fmaxf(g, xb[s * DIM + d]);
    for (int s = part * 64; s < part * 64 + 64; ++s) {
        float* row = x + ((size_t)(b * NSEG + s)) * D2;
        row[d] = g;
        row[DIM + d] = xb[s * DIM + d];
    }
}

// ---------------------------------------------------------------------------
// LayerNorm over 512:  h = (x-mu)*rstd*g + b
// ---------------------------------------------------------------------------
__global__ __launch_bounds__(128) void k_ln(const float* __restrict__ x,
                                            const float* __restrict__ g,
                                            const float* __restrict__ bta,
                                            float* __restrict__ h) {
    const int row = blockIdx.x, t = threadIdx.x;   // 128 thr * 4 elems
    const float4 v = *(const float4*)(x + (size_t)row * D2 + t * 4);
    float s = v.x + v.y + v.z + v.w;
    float ss = v.x * v.x + v.y * v.y + v.z * v.z + v.w * v.w;
    #pragma unroll
    for (int o = 32; o; o >>= 1) { s += __shfl_down(s, o); ss += __shfl_down(ss, o); }
    __shared__ float red[4];
    if ((t & 63) == 0) { red[(t >> 6) * 2] = s; red[(t >> 6) * 2 + 1] = ss; }
    __syncthreads();
    s = red[0] + red[2]; ss = red[1] + red[3];
    const float mu = s * (1.f / D2);
    const float rstd = rsqrtf(ss * (1.f / D2) - mu * mu + 1e-5f);
    const float4 g4 = *(const float4*)(g + t * 4);
    const float4 b4 = *(const float4*)(bta + t * 4);
    float4 o4;
    o4.x = (v.x - mu) * rstd * g4.x + b4.x;
    o4.y = (v.y - mu) * rstd * g4.y + b4.y;
    o4.z = (v.z - mu) * rstd * g4.z + b4.z;
    o4.w = (v.w - mu) * rstd * g4.w + b4.w;
    *(float4*)(h + (size_t)row * D2 + t * 4) = o4;
}

// ---------------------------------------------------------------------------
// fp32 tiled GEMM core: 64x64 tile, BK=16, 256 thr, 4x4 per thread
// A row-major [M,lda] (pre-offset to tile row), B row-major [K,ldb] (pre-offset to tile col)
// ---------------------------------------------------------------------------
__device__ __forceinline__ void gemm_tile(const float* __restrict__ A, int lda,
                                          const float* __restrict__ Bm, int ldb,
                                          int K, float acc[4][4],
                                          float (*As)[68], float (*Bs)[64]) {
    const int t = threadIdx.x;
    const int arow = t >> 2, akg = t & 3;       // A: 64 rows x 4 k-groups
    const int bk = t >> 4, bng = t & 15;        // B: 16 k x 16 n-groups
    const int tx = t & 15, ty = t >> 4;
    for (int k0 = 0; k0 < K; k0 += 16) {
        const float4 av = *(const float4*)(A + (size_t)arow * lda + k0 + akg * 4);
        const float4 bv = *(const float4*)(Bm + (size_t)(k0 + bk) * ldb + bng * 4);
        __syncthreads();
        As[akg * 4 + 0][arow] = av.x;
        As[akg * 4 + 1][arow] = av.y;
        As[akg * 4 + 2][arow] = av.z;
        As[akg * 4 + 3][arow] = av.w;
        *(float4*)(&Bs[bk][bng * 4]) = bv;
        __syncthreads();
        #pragma unroll
        for (int u = 0; u < 16; ++u) {
            const float4 a4 = *(const float4*)(&As[u][ty * 4]);
            const float4 b4 = *(const float4*)(&Bs[u][tx * 4]);
            const float a[4] = {a4.x, a4.y, a4.z, a4.w};
            const float b[4] = {b4.x, b4.y, b4.z, b4.w};
            #pragma unroll
            for (int i = 0; i < 4; ++i)
                #pragma unroll
                for (int j = 0; j < 4; ++j)
                    acc[i][j] = fmaf(a[i], b[j], acc[i][j]);
        }
    }
}

// qkv = h @ Wqkv, scatter into q/k/v [BH, N, DH]
__global__ __launch_bounds__(256) void k_gemm_qkv(const float* __restrict__ H,
                                                  const float* __restrict__ W,
                                                  float* __restrict__ qkv) {
    __shared__ float As[16][68], Bs[16][64];
    const int m0 = blockIdx.x * 64, n0 = blockIdx.y * 64;
    float acc[4][4] = {};
    gemm_tile(H + (size_t)m0 * D2, D2, W + n0, 3 * INNER, D2, acc, As, Bs);
    const int which = n0 / INNER;            // 0=q 1=k 2=v
    const int hd = (n0 % INNER) >> 6;        // head
    const int t = threadIdx.x, tx = t & 15, ty = t >> 4;
    float* dst = qkv + (size_t)which * (NB * HEADS * NSEG * DHD);
    #pragma unroll
    for (int i = 0; i < 4; ++i) {
        const int row = m0 + ty * 4 + i;
        const int b = row >> 8, n = row & 255;
        float4 o4 = make_float4(acc[i][0], acc[i][1], acc[i][2], acc[i][3]);
        *(float4*)(dst + (((size_t)(b * HEADS + hd) * NSEG + n) * DHD) + tx * 4) = o4;
    }
}

// C(out[row,ncol]) = X + A@W + bias   (residual in-place on X)
__global__ __launch_bounds__(256) void k_gemm_res(const float* __restrict__ A,
                                                  const float* __restrict__ W,
                                                  const float* __restrict__ bias,
                                                  float* __restrict__ X, int K) {
    __shared__ float As[16][68], Bs[16][64];
    const int m0 = blockIdx.x * 64, n0 = blockIdx.y * 64;
    float acc[4][4] = {};
    gemm_tile(A + (size_t)m0 * K, K, W + n0, D2, K, acc, As, Bs);
    const int t = threadIdx.x, tx = t & 15, ty = t >> 4;
    const float4 b4 = *(const float4*)(bias + n0 + tx * 4);
    #pragma unroll
    for (int i = 0; i < 4; ++i) {
        float* xp = X + (size_t)(m0 + ty * 4 + i) * D2 + n0 + tx * 4;
        float4 xv = *(const float4*)xp;
        xv.x += acc[i][0] + b4.x;
        xv.y += acc[i][1] + b4.y;
        xv.z += acc[i][2] + b4.z;
        xv.w += acc[i][3] + b4.w;
        *(float4*)xp = xv;
    }
}

// H1 = gelu(h @ W1 + b1)
__global__ __launch_bounds__(256) void k_gemm_gelu(const float* __restrict__ A,
                                                   const float* __restrict__ W,
                                                   const float* __restrict__ bias,
                                                   float* __restrict__ H1) {
    __shared__ float As[16][68], Bs[16][64];
    const int m0 = blockIdx.x * 64, n0 = blockIdx.y * 64;
    float acc[4][4] = {};
    gemm_tile(A + (size_t)m0 * D2, D2, W + n0, MLPD, D2, acc, As, Bs);
    const int t = threadIdx.x, tx = t & 15, ty = t >> 4;
    const float4 b4 = *(const float4*)(bias + n0 + tx * 4);
    const float bb[4] = {b4.x, b4.y, b4.z, b4.w};
    #pragma unroll
    for (int i = 0; i < 4; ++i) {
        float4 o4;
        float* o = (float*)&o4;
        #pragma unroll
        for (int j = 0; j < 4; ++j) {
            float v = acc[i][j] + bb[j];
            o[j] = 0.5f * v * (1.f + erff(v * 0.70710678118654752f));
        }
        *(float4*)(H1 + (size_t)(m0 + ty * 4 + i) * MLPD + n0 + tx * 4) = o4;
    }
}

// scores[bh,i,j] = 0.125 * q[bh,i,:] . k[bh,j,:]
__global__ __launch_bounds__(256) void k_qk(const float* __restrict__ q,
                                            const float* __restrict__ kmat,
                                            float* __restrict__ sc) {
    __shared__ float Qs[16][68], Ks[16][68];
    const int bh = blockIdx.z;
    const int t = threadIdx.x;
    const int arow = t >> 2, akg = t & 3, tx = t & 15, ty = t >> 4;
    const float* qb = q + ((size_t)bh * NSEG + blockIdx.x * 64) * DHD;
    const float* kb = kmat + ((size_t)bh * NSEG + blockIdx.y * 64) * DHD;
    float acc[4][4] = {};
    for (int k0 = 0; k0 < DHD; k0 += 16) {
        const float4 qv = *(const float4*)(qb + arow * DHD + k0 + akg * 4);
        const float4 kv = *(const float4*)(kb + arow * DHD + k0 + akg * 4);
        __syncthreads();
        Qs[akg * 4 + 0][arow] = qv.x; Qs[akg * 4 + 1][arow] = qv.y;
        Qs[akg * 4 + 2][arow] = qv.z; Qs[akg * 4 + 3][arow] = qv.w;
        Ks[akg * 4 + 0][arow] = kv.x; Ks[akg * 4 + 1][arow] = kv.y;
        Ks[akg * 4 + 2][arow] = kv.z; Ks[akg * 4 + 3][arow] = kv.w;
        __syncthreads();
        #pragma unroll
        for (int u = 0; u < 16; ++u) {
            const float4 a4 = *(const float4*)(&Qs[u][ty * 4]);
            const float4 b4 = *(const float4*)(&Ks[u][tx * 4]);
            const float a[4] = {a4.x, a4.y, a4.z, a4.w};
            const float b[4] = {b4.x, b4.y, b4.z, b4.w};
            #pragma unroll
            for (int i = 0; i < 4; ++i)
                #pragma unroll
                for (int j = 0; j < 4; ++j)
                    acc[i][j] = fmaf(a[i], b[j], acc[i][j]);
        }
    }
    float* sb = sc + (size_t)bh * NSEG * NSEG + (size_t)(blockIdx.x * 64) * NSEG + blockIdx.y * 64;
    #pragma unroll
    for (int i = 0; i < 4; ++i) {
        float4 o4 = make_float4(acc[i][0] * 0.125f, acc[i][1] * 0.125f,
                                acc[i][2] * 0.125f, acc[i][3] * 0.125f);
        *(float4*)(sb + (size_t)(ty * 4 + i) * NSEG + tx * 4) = o4;
    }
}

// in-place row softmax, rows of 256 (one wave per row, 4 rows/block)
__global__ __launch_bounds__(256) void k_softmax(float* __restrict__ sc) {
    const int row = blockIdx.x * 4 + (threadIdx.x >> 6);
    const int l = threadIdx.x & 63;
    float* p = sc + (size_t)row * 256 + l * 4;
    float4 v = *(float4*)p;
    float m = fmaxf(fmaxf(v.x, v.y), fmaxf(v.z, v.w));
    #pragma unroll
    for (int o = 32; o; o >>= 1) m = fmaxf(m, __shfl_xor(m, o));
    v.x = __expf(v.x - m); v.y = __expf(v.y - m);
    v.z = __expf(v.z - m); v.w = __expf(v.w - m);
    float s = v.x + v.y + v.z + v.w;
    #pragma unroll
    for (int o = 32; o; o >>= 1) s += __shfl_xor(s, o);
    const float r = 1.f / s;
    v.x *= r; v.y *= r; v.z *= r; v.w *= r;
    *(float4*)p = v;
}

// o[b, i, h*64+dh] = attn[bh] @ v[bh]
__global__ __launch_bounds__(256) void k_pv(const float* __restrict__ sc,
                                            const float* __restrict__ vmat,
                                            float* __restrict__ o) {
    __shared__ float As[16][68], Bs[16][64];
    const int bh = blockIdx.z;
    const int m0 = blockIdx.x * 64;
    float acc[4][4] = {};
    gemm_tile(sc + (size_t)bh * NSEG * NSEG + (size_t)m0 * NSEG, NSEG,
              vmat + (size_t)bh * NSEG * DHD, DHD, NSEG, acc, As, Bs);
    const int t = threadIdx.x, tx = t & 15, ty = t >> 4;
    float* Cp = o + (size_t)(bh >> 3) * NSEG * INNER + (bh & 7) * DHD;
    #pragma unroll
    for (int i = 0; i < 4; ++i) {
        float4 o4 = make_float4(acc[i][0], acc[i][1], acc[i][2], acc[i][3]);
        *(float4*)(Cp + (size_t)(m0 + ty * 4 + i) * INNER + tx * 4) = o4;
    }
}

// final: out = LN(x; lnf) @ W_head + b_head
__global__ __launch_bounds__(128) void k_head(const float* __restrict__ x,
                                              const float* __restrict__ g,
                                              const float* __restrict__ bta,
                                              const float* __restrict__ Wh,
                                              const float* __restrict__ bhd,
                                              float* __restrict__ out) {
    const int row = blockIdx.x, t = threadIdx.x;
    const float4 v = *(const float4*)(x + (size_t)row * D2 + t * 4);
    float s = v.x + v.y + v.z + v.w;
    float ss = v.x * v.x + v.y * v.y + v.z * v.z + v.w * v.w;
    #pragma unroll
    for (int o = 32; o; o >>= 1) { s += __shfl_down(s, o); ss += __shfl_down(ss, o); }
    __shared__ float red[4];
    if ((t & 63) == 0) { red[(t >> 6) * 2] = s; red[(t >> 6) * 2 + 1] = ss; }
    __syncthreads();
    s = red[0] + red[2]; ss = red[1] + red[3];
    const float mu = s * (1.f / D2);
    const float rstd = rsqrtf(ss * (1.f / D2) - mu * mu + 1e-5f);
    const float4 g4 = *(const float4*)(g + t * 4);
    const float4 b4 = *(const float4*)(bta + t * 4);
    const float hv[4] = {(v.x - mu) * rstd * g4.x + b4.x,
                         (v.y - mu) * rstd * g4.y + b4.y,
                         (v.z - mu) * rstd * g4.z + b4.z,
                         (v.w - mu) * rstd * g4.w + b4.w};
    float p[4] = {0, 0, 0, 0};
    #pragma unroll
    for (int i = 0; i < 4; ++i) {
        const float4 w = *(const float4*)(Wh + (size_t)(t * 4 + i) * NCLS);
        p[0] = fmaf(hv[i], w.x, p[0]); p[1] = fmaf(hv[i], w.y, p[1]);
        p[2] = fmaf(hv[i], w.z, p[2]); p[3] = fmaf(hv[i], w.w, p[3]);
    }
    #pragma unroll
    for (int o = 32; o; o >>= 1)
        #pragma unroll
        for (int c2 = 0; c2 < 4; ++c2) p[c2] += __shfl_down(p[c2], o);
    __shared__ float red2[2][4];
    if ((t & 63) == 0) {
        #pragma unroll
        for (int c2 = 0; c2 < 4; ++c2) red2[t >> 6][c2] = p[c2];
    }
    __syncthreads();
    if (t < 4) out[(size_t)row * NCLS + t] = red2[0][t] + red2[1][t] + bhd[t];
}

// ---------------------------------------------------------------------------
extern "C" void kernel_launch(void* const* d_in, const int* in_sizes, int n_in,
                              void* d_out, int out_size, void* d_ws, size_t ws_size,
                              hipStream_t stream) {
    const float* feature = (const float*)d_in[1];
    const int*   sp      = (const int*)d_in[2];
    const float* Wp      = (const float*)d_in[3];
    const float* bp      = (const float*)d_in[4];
    const float* ln1g    = (const float*)d_in[5];
    const float* ln1b    = (const float*)d_in[6];
    const float* Wqkv    = (const float*)d_in[7];
    const float* Wo      = (const float*)d_in[8];
    const float* bo      = (const float*)d_in[9];
    const float* ln2g    = (const float*)d_in[10];
    const float* ln2b    = (const float*)d_in[11];
    const float* W1      = (const float*)d_in[12];
    const float* b1      = (const float*)d_in[13];
    const float* W2      = (const float*)d_in[14];
    const float* b2      = (const float*)d_in[15];
    const float* lnfg    = (const float*)d_in[16];
    const float* lnfb    = (const float*)d_in[17];
    const float* Wh      = (const float*)d_in[18];
    const float* bhd     = (const float*)d_in[19];
    float* out = (float*)d_out;
    float* ws  = (float*)d_ws;

    // workspace layout (floats)
    float* x   = ws + 0;          // [2048,512]
    float* x0  = ws + 1048576;    // [2048,256]
    float* hln = ws + 1572864;    // [2048,512]
    float* h1  = ws + 2621440;    // [2048,1024]
    float* qkv = ws + 4718592;    // q,k,v each [64,256,64]
    float* sc  = ws + 7864320;    // [64,256,256]
    float* o   = ws + 12058624;   // [2048,512]

    k_init_x0<<<2048, 256, 0, stream>>>(x0, bp);
    k_patch<<<NPIX / PPB, 256, 0, stream>>>(feature, sp, Wp, x0);
    k_concat<<<dim3(NB, 4), 256, 0, stream>>>(x0, x);

    for (int d = 0; d < DEPTH; ++d) {
        k_ln<<<NTOK, 128, 0, stream>>>(x, ln1g + d * D2, ln1b + d * D2, hln);
        k_gemm_qkv<<<dim3(32, 24), 256, 0, stream>>>(hln, Wqkv + (size_t)d * D2 * 3 * INNER, qkv);
        k_qk<<<dim3(4, 4, 64), 256, 0, stream>>>(qkv, qkv + 1048576, sc);
        k_softmax<<<4096, 256, 0, stream>>>(sc);
        k_pv<<<dim3(4, 1, 64), 256, 0, stream>>>(sc, qkv + 2097152, o);
        k_gemm_res<<<dim3(32, 8), 256, 0, stream>>>(o, Wo + (size_t)d * INNER * D2,
                                                    bo + d * D2, x, INNER);
        k_ln<<<NTOK, 128, 0, stream>>>(x, ln2g + d * D2, ln2b + d * D2, hln);
        k_gemm_gelu<<<dim3(32, 16), 256, 0, stream>>>(hln, W1 + (size_t)d * D2 * MLPD,
                                                      b1 + d * MLPD, h1);
        k_gemm_res<<<dim3(32, 8), 256, 0, stream>>>(h1, W2 + (size_t)d * MLPD * D2,
                                                    b2 + d * D2, x, MLPD);
    }
    k_head<<<NTOK, 128, 0, stream>>>(x, lnfg, lnfb, Wh, bhd, out);
}

// Round 6
// 1103.410 us; speedup vs baseline: 1.3589x; 1.3589x over previous
//
#include <hip/hip_runtime.h>
#include <hip/hip_bf16.h>
#include <math.h>

// Problem constants
#define NB 8
#define NC 64
#define NS 64
#define NPIX 4096      // NS*NS
#define NSEG 256
#define DIM 256
#define DEPTH 4
#define HEADS 8
#define DHD 64
#define MLPD 1024
#define NCLS 4
#define D2 512
#define INNER 512
#define NTOK 2048      // NB*NSEG

typedef unsigned short u16;
typedef unsigned int u32;
typedef __attribute__((ext_vector_type(4))) float f32x4;
typedef __attribute__((ext_vector_type(8))) short short8;

// ---- fp32 -> (hi,lo) bf16 split, RNE --------------------------------------
__device__ __forceinline__ u16 bf16_rne(float x) {
    u32 u = __float_as_uint(x);
    return (u16)((u + 0x7FFFu + ((u >> 16) & 1u)) >> 16);
}
__device__ __forceinline__ void split2(float x, u16& h, u16& l) {
    h = bf16_rne(x);
    float hf = __uint_as_float((u32)h << 16);
    l = bf16_rne(x - hf);
}

// ---------------------------------------------------------------------------
// Patch embedding
// ---------------------------------------------------------------------------
__global__ __launch_bounds__(256) void k_init_x0(float* __restrict__ x0,
                                                 const float* __restrict__ bp) {
    int idx = blockIdx.x * 256 + threadIdx.x;
    x0[idx] = bp[idx & (DIM - 1)];
}

#define PPB 4
__global__ __launch_bounds__(256) void k_patch(const float* __restrict__ feature,
                                               const int* __restrict__ sp,
                                               const float* __restrict__ Wp,
                                               float* __restrict__ x0) {
    __shared__ __align__(16) float f[NB * NC][PPB];     // 8 KB
    __shared__ int seg[NB][PPB];
    const int p0 = blockIdx.x * PPB;
    const int t = threadIdx.x;
    const float* feat2 = feature + (size_t)2 * NB * NC * NPIX;
    #pragma unroll
    for (int i = 0; i < 2; ++i) {
        int pair = t + i * 256;            // b*64+c
        *(float4*)&f[pair][0] = *(const float4*)&feat2[(size_t)pair * NPIX + p0];
    }
    if (t < NB * PPB) seg[t >> 2][t & 3] = sp[(t >> 2) * NPIX + p0 + (t & 3)];
    __syncthreads();
    const int d = t;   // 0..255
    for (int q = 0; q < PPB; ++q) {
        float acc[NB];
        #pragma unroll
        for (int b = 0; b < NB; ++b) acc[b] = 0.f;
        const float* wcol = Wp + (size_t)(p0 + q) * DIM + d;
        #pragma unroll 8
        for (int c = 0; c < NC; ++c) {
            float w = wcol[(size_t)c * NPIX * DIM];   // 1 KB coalesced per (c,q)
            #pragma unroll
            for (int b = 0; b < NB; ++b) acc[b] = fmaf(f[b * NC + c][q], w, acc[b]);
        }
        #pragma unroll
        for (int b = 0; b < NB; ++b)
            atomicAdd(&x0[((b * NSEG) + seg[b][q]) * DIM + d], acc[b]);
    }
}

__global__ __launch_bounds__(256) void k_concat(const float* __restrict__ x0,
                                                float* __restrict__ x) {
    const int b = blockIdx.x, part = blockIdx.y;
    const int d = threadIdx.x;
    const float* xb = x0 + (size_t)b * NSEG * DIM;
    float g = -INFINITY;
    for (int s = 0; s < NSEG; ++s) g = fmaxf(g, xb[s * DIM + d]);
    for (int s = part * 16; s < part * 16 + 16; ++s) {
        float* row = x + ((size_t)(b * NSEG + s)) * D2;
        row[d] = g;
        row[DIM + d] = xb[s * DIM + d];
    }
}

// ---------------------------------------------------------------------------
// LayerNorm over 512 -> split bf16 (hi/lo) output
// ---------------------------------------------------------------------------
__global__ __launch_bounds__(128) void k_ln(const float* __restrict__ x,
                                            const float* __restrict__ g,
                                            const float* __restrict__ bta,
                                            u16* __restrict__ outH,
                                            u16* __restrict__ outL) {
    const int row = blockIdx.x, t = threadIdx.x;
    const float4 v = *(const float4*)(x + (size_t)row * D2 + t * 4);
    float s = v.x + v.y + v.z + v.w;
    float ss = v.x * v.x + v.y * v.y + v.z * v.z + v.w * v.w;
    #pragma unroll
    for (int o = 32; o; o >>= 1) { s += __shfl_down(s, o); ss += __shfl_down(ss, o); }
    __shared__ float red[4];
    if ((t & 63) == 0) { red[(t >> 6) * 2] = s; red[(t >> 6) * 2 + 1] = ss; }
    __syncthreads();
    s = red[0] + red[2]; ss = red[1] + red[3];
    const float mu = s * (1.f / D2);
    const float rstd = rsqrtf(ss * (1.f / D2) - mu * mu + 1e-5f);
    const float4 g4 = *(const float4*)(g + t * 4);
    const float4 b4 = *(const float4*)(bta + t * 4);
    float o4[4] = {(v.x - mu) * rstd * g4.x + b4.x,
                   (v.y - mu) * rstd * g4.y + b4.y,
                   (v.z - mu) * rstd * g4.z + b4.z,
                   (v.w - mu) * rstd * g4.w + b4.w};
    u16 h[4], l[4];
    #pragma unroll
    for (int i = 0; i < 4; ++i) split2(o4[i], h[i], l[i]);
    *(ushort4*)(outH + (size_t)row * D2 + t * 4) = make_ushort4(h[0], h[1], h[2], h[3]);
    *(ushort4*)(outL + (size_t)row * D2 + t * 4) = make_ushort4(l[0], l[1], l[2], l[3]);
}

// ---------------------------------------------------------------------------
// Weight transpose + split:  src fp32 [K][N] -> dstH/dstL bf16 [N][K]
// ---------------------------------------------------------------------------
__device__ __forceinline__ void cvt_tile(const float* __restrict__ src, int K, int N,
                                         u16* __restrict__ dH, u16* __restrict__ dL,
                                         int k0, int n0) {
    __shared__ __align__(16) float ls[32][33];
    const int t = threadIdx.x;
    const int r = t >> 3, cg = t & 7;
    const float4 v = *(const float4*)(src + (size_t)(k0 + r) * N + n0 + cg * 4);
    ls[r][cg * 4 + 0] = v.x; ls[r][cg * 4 + 1] = v.y;
    ls[r][cg * 4 + 2] = v.z; ls[r][cg * 4 + 3] = v.w;
    __syncthreads();
    u16 h[4], l[4];
    #pragma unroll
    for (int i = 0; i < 4; ++i) split2(ls[cg * 4 + i][r], h[i], l[i]);
    *(ushort4*)(dH + (size_t)(n0 + r) * K + k0 + cg * 4) = make_ushort4(h[0], h[1], h[2], h[3]);
    *(ushort4*)(dL + (size_t)(n0 + r) * K + k0 + cg * 4) = make_ushort4(l[0], l[1], l[2], l[3]);
}

__global__ __launch_bounds__(256) void k_cvtT(const float* __restrict__ src,
                                              u16* __restrict__ dH, u16* __restrict__ dL,
                                              int K, int N) {
    cvt_tile(src, K, N, dH, dL, blockIdx.x * 32, blockIdx.y * 32);
}

__global__ __launch_bounds__(256) void k_cvtT3(const float* __restrict__ sO,
                                               const float* __restrict__ s1,
                                               const float* __restrict__ s2,
                                               u16* __restrict__ wb) {
    int K, N; const float* src; u16 *dH, *dL;
    if (blockIdx.z == 0)      { K = 512;  N = 512;  src = sO; dH = wb;           dL = wb + 262144; }
    else if (blockIdx.z == 1) { K = 512;  N = 1024; src = s1; dH = wb + 524288;  dL = wb + 1048576; }
    else                      { K = 1024; N = 512;  src = s2; dH = wb + 1572864; dL = wb + 2097152; }
    const int k0 = blockIdx.x * 32, n0 = blockIdx.y * 32;
    if (k0 >= K || n0 >= N) return;
    cvt_tile(src, K, N, dH, dL, k0, n0);
}

// ---------------------------------------------------------------------------
// Split-bf16 MFMA GEMM: C[M,NN] = (Ah+Al)[M,K] @ (Bh+Bl)^T[NN,K]
// 128x128 block tile, BK=32, 4 waves (2x2), wave tile 64x64 (4x4 frags 16x16x32)
// Staging: 2 thr/row x 32B (two uint4 = 16 bf16 each) covers full BK=32.
// MODE 0: scatter to qkv; MODE 1: X += acc + bias; MODE 2: gelu -> split bf16
// ---------------------------------------------------------------------------
template<int K, int NN, int MODE>
__global__ __launch_bounds__(256) void k_mfmm(const u16* __restrict__ Ah,
                                              const u16* __restrict__ Al,
                                              const u16* __restrict__ Bh,
                                              const u16* __restrict__ Bl,
                                              const float* __restrict__ bias,
                                              float* __restrict__ Cf,
                                              u16* __restrict__ CoH,
                                              u16* __restrict__ CoL) {
    __shared__ __align__(16) u16 AsH[128][40], AsL[128][40], BsH[128][40], BsL[128][40];  // 40 KB
    const int m0 = blockIdx.x * 128, n0 = blockIdx.y * 128;
    const int t = threadIdx.x;
    const int srow = t >> 1, soff = (t & 1) * 16;   // 2 thr/row, 16 bf16 each
    const int lane = t & 63;
    const int wr = (t >> 7) & 1, wc = (t >> 6) & 1;
    const int lrow = lane & 15, lk = lane >> 4;

    const u16* pAh = Ah + (size_t)(m0 + srow) * K + soff;
    const u16* pAl = Al + (size_t)(m0 + srow) * K + soff;
    const u16* pBh = Bh + (size_t)(n0 + srow) * K + soff;
    const u16* pBl = Bl + (size_t)(n0 + srow) * K + soff;

    uint4 rAh0 = *(const uint4*)pAh,       rAh1 = *(const uint4*)(pAh + 8);
    uint4 rAl0 = *(const uint4*)pAl,       rAl1 = *(const uint4*)(pAl + 8);
    uint4 rBh0 = *(const uint4*)pBh,       rBh1 = *(const uint4*)(pBh + 8);
    uint4 rBl0 = *(const uint4*)pBl,       rBl1 = *(const uint4*)(pBl + 8);

    f32x4 acc[4][4];
    #pragma unroll
    for (int i = 0; i < 4; ++i)
        #pragma unroll
        for (int j = 0; j < 4; ++j) acc[i][j] = (f32x4){0.f, 0.f, 0.f, 0.f};

    #pragma unroll 1
    for (int k0 = 0; k0 < K; k0 += 32) {
        __syncthreads();
        *(uint4*)&AsH[srow][soff] = rAh0;  *(uint4*)&AsH[srow][soff + 8] = rAh1;
        *(uint4*)&AsL[srow][soff] = rAl0;  *(uint4*)&AsL[srow][soff + 8] = rAl1;
        *(uint4*)&BsH[srow][soff] = rBh0;  *(uint4*)&BsH[srow][soff + 8] = rBh1;
        *(uint4*)&BsL[srow][soff] = rBl0;  *(uint4*)&BsL[srow][soff + 8] = rBl1;
        __syncthreads();
        if (k0 + 32 < K) {
            rAh0 = *(const uint4*)(pAh + k0 + 32);  rAh1 = *(const uint4*)(pAh + k0 + 40);
            rAl0 = *(const uint4*)(pAl + k0 + 32);  rAl1 = *(const uint4*)(pAl + k0 + 40);
            rBh0 = *(const uint4*)(pBh + k0 + 32);  rBh1 = *(const uint4*)(pBh + k0 + 40);
            rBl0 = *(const uint4*)(pBl + k0 + 32);  rBl1 = *(const uint4*)(pBl + k0 + 40);
        }
        short8 ah[4], al[4], bh[4], bl[4];
        #pragma unroll
        for (int i = 0; i < 4; ++i) {
            ah[i] = *(const short8*)&AsH[wr * 64 + i * 16 + lrow][lk * 8];
            al[i] = *(const short8*)&AsL[wr * 64 + i * 16 + lrow][lk * 8];
            bh[i] = *(const short8*)&BsH[wc * 64 + i * 16 + lrow][lk * 8];
            bl[i] = *(const short8*)&BsL[wc * 64 + i * 16 + lrow][lk * 8];
        }
        #pragma unroll
        for (int i = 0; i < 4; ++i)
            #pragma unroll
            for (int j = 0; j < 4; ++j) {
                acc[i][j] = __builtin_amdgcn_mfma_f32_16x16x32_bf16(ah[i], bh[j], acc[i][j], 0, 0, 0);
                acc[i][j] = __builtin_amdgcn_mfma_f32_16x16x32_bf16(ah[i], bl[j], acc[i][j], 0, 0, 0);
                acc[i][j] = __builtin_amdgcn_mfma_f32_16x16x32_bf16(al[i], bh[j], acc[i][j], 0, 0, 0);
            }
    }
    // epilogue: D frag layout col=lane&15, row=(lane>>4)*4+reg   [m89/m91]
    #pragma unroll
    for (int i = 0; i < 4; ++i) {
        #pragma unroll
        for (int j = 0; j < 4; ++j) {
            #pragma unroll
            for (int r = 0; r < 4; ++r) {
                const int row = m0 + wr * 64 + i * 16 + lk * 4 + r;
                const int col = n0 + wc * 64 + j * 16 + lrow;
                float v = acc[i][j][r];
                if (MODE == 0) {
                    const int which = col >> 9, hd = (col >> 6) & 7, dh = col & 63;
                    const int b = row >> 8, nn = row & 255;
                    Cf[(size_t)which * (NB * HEADS * NSEG * DHD) +
                       ((size_t)(b * HEADS + hd) * NSEG + nn) * DHD + dh] = v;
                } else if (MODE == 1) {
                    float* xp = Cf + (size_t)row * NN + col;
                    *xp += v + bias[col];
                } else {
                    v += bias[col];
                    float gl = 0.5f * v * (1.f + erff(v * 0.70710678118654752f));
                    u16 h, l; split2(gl, h, l);
                    CoH[(size_t)row * NN + col] = h;
                    CoL[(size_t)row * NN + col] = l;
                }
            }
        }
    }
}

// ---------------------------------------------------------------------------
// fp32 tiled GEMM core (kept for attention qk / pv)
// ---------------------------------------------------------------------------
__device__ __forceinline__ void gemm_tile(const float* __restrict__ A, int lda,
                                          const float* __restrict__ Bm, int ldb,
                                          int K, float acc[4][4],
                                          float (*As)[68], float (*Bs)[64]) {
    const int t = threadIdx.x;
    const int arow = t >> 2, akg = t & 3;
    const int bk = t >> 4, bng = t & 15;
    const int tx = t & 15, ty = t >> 4;
    for (int k0 = 0; k0 < K; k0 += 16) {
        const float4 av = *(const float4*)(A + (size_t)arow * lda + k0 + akg * 4);
        const float4 bv = *(const float4*)(Bm + (size_t)(k0 + bk) * ldb + bng * 4);
        __syncthreads();
        As[akg * 4 + 0][arow] = av.x;
        As[akg * 4 + 1][arow] = av.y;
        As[akg * 4 + 2][arow] = av.z;
        As[akg * 4 + 3][arow] = av.w;
        *(float4*)(&Bs[bk][bng * 4]) = bv;
        __syncthreads();
        #pragma unroll
        for (int u = 0; u < 16; ++u) {
            const float4 a4 = *(const float4*)(&As[u][ty * 4]);
            const float4 b4 = *(const float4*)(&Bs[u][tx * 4]);
            const float a[4] = {a4.x, a4.y, a4.z, a4.w};
            const float b[4] = {b4.x, b4.y, b4.z, b4.w};
            #pragma unroll
            for (int i = 0; i < 4; ++i)
                #pragma unroll
                for (int j = 0; j < 4; ++j)
                    acc[i][j] = fmaf(a[i], b[j], acc[i][j]);
        }
    }
}

__global__ __launch_bounds__(256) void k_qk(const float* __restrict__ q,
                                            const float* __restrict__ kmat,
                                            float* __restrict__ sc) {
    __shared__ __align__(16) float Qs[16][68], Ks[16][68];
    const int bh = blockIdx.z;
    const int t = threadIdx.x;
    const int arow = t >> 2, akg = t & 3, tx = t & 15, ty = t >> 4;
    const float* qb = q + ((size_t)bh * NSEG + blockIdx.x * 64) * DHD;
    const float* kb = kmat + ((size_t)bh * NSEG + blockIdx.y * 64) * DHD;
    float acc[4][4] = {};
    for (int k0 = 0; k0 < DHD; k0 += 16) {
        const float4 qv = *(const float4*)(qb + arow * DHD + k0 + akg * 4);
        const float4 kv = *(const float4*)(kb + arow * DHD + k0 + akg * 4);
        __syncthreads();
        Qs[akg * 4 + 0][arow] = qv.x; Qs[akg * 4 + 1][arow] = qv.y;
        Qs[akg * 4 + 2][arow] = qv.z; Qs[akg * 4 + 3][arow] = qv.w;
        Ks[akg * 4 + 0][arow] = kv.x; Ks[akg * 4 + 1][arow] = kv.y;
        Ks[akg * 4 + 2][arow] = kv.z; Ks[akg * 4 + 3][arow] = kv.w;
        __syncthreads();
        #pragma unroll
        for (int u = 0; u < 16; ++u) {
            const float4 a4 = *(const float4*)(&Qs[u][ty * 4]);
            const float4 b4 = *(const float4*)(&Ks[u][tx * 4]);
            const float a[4] = {a4.x, a4.y, a4.z, a4.w};
            const float b[4] = {b4.x, b4.y, b4.z, b4.w};
            #pragma unroll
            for (int i = 0; i < 4; ++i)
                #pragma unroll
                for (int j = 0; j < 4; ++j)
                    acc[i][j] = fmaf(a[i], b[j], acc[i][j]);
        }
    }
    float* sb = sc + (size_t)bh * NSEG * NSEG + (size_t)(blockIdx.x * 64) * NSEG + blockIdx.y * 64;
    #pragma unroll
    for (int i = 0; i < 4; ++i) {
        float4 o4 = make_float4(acc[i][0] * 0.125f, acc[i][1] * 0.125f,
                                acc[i][2] * 0.125f, acc[i][3] * 0.125f);
        *(float4*)(sb + (size_t)(ty * 4 + i) * NSEG + tx * 4) = o4;
    }
}

__global__ __launch_bounds__(256) void k_softmax(float* __restrict__ sc) {
    const int row = blockIdx.x * 4 + (threadIdx.x >> 6);
    const int l = threadIdx.x & 63;
    float* p = sc + (size_t)row * 256 + l * 4;
    float4 v = *(float4*)p;
    float m = fmaxf(fmaxf(v.x, v.y), fmaxf(v.z, v.w));
    #pragma unroll
    for (int o = 32; o; o >>= 1) m = fmaxf(m, __shfl_xor(m, o));
    v.x = __expf(v.x - m); v.y = __expf(v.y - m);
    v.z = __expf(v.z - m); v.w = __expf(v.w - m);
    float s = v.x + v.y + v.z + v.w;
    #pragma unroll
    for (int o = 32; o; o >>= 1) s += __shfl_xor(s, o);
    const float r = 1.f / s;
    v.x *= r; v.y *= r; v.z *= r; v.w *= r;
    *(float4*)p = v;
}

// o (split bf16) = attn @ v
__global__ __launch_bounds__(256) void k_pv(const float* __restrict__ sc,
                                            const float* __restrict__ vmat,
                                            u16* __restrict__ oH,
                                            u16* __restrict__ oL) {
    __shared__ __align__(16) float As[16][68], Bs[16][64];
    const int bh = blockIdx.z;
    const int m0 = blockIdx.x * 64;
    float acc[4][4] = {};
    gemm_tile(sc + (size_t)bh * NSEG * NSEG + (size_t)m0 * NSEG, NSEG,
              vmat + (size_t)bh * NSEG * DHD, DHD, NSEG, acc, As, Bs);
    const int t = threadIdx.x, tx = t & 15, ty = t >> 4;
    #pragma unroll
    for (int i = 0; i < 4; ++i) {
        const size_t idx = (size_t)(bh >> 3) * NSEG * INNER + (bh & 7) * DHD +
                           (size_t)(m0 + ty * 4 + i) * INNER + tx * 4;
        u16 h[4], l[4];
        #pragma unroll
        for (int j = 0; j < 4; ++j) split2(acc[i][j], h[j], l[j]);
        *(ushort4*)(oH + idx) = make_ushort4(h[0], h[1], h[2], h[3]);
        *(ushort4*)(oL + idx) = make_ushort4(l[0], l[1], l[2], l[3]);
    }
}

__global__ __launch_bounds__(128) void k_head(const float* __restrict__ x,
                                              const float* __restrict__ g,
                                              const float* __restrict__ bta,
                                              const float* __restrict__ Wh,
                                              const float* __restrict__ bhd,
                                              float* __restrict__ out) {
    const int row = blockIdx.x, t = threadIdx.x;
    const float4 v = *(const float4*)(x + (size_t)row * D2 + t * 4);
    float s = v.x + v.y + v.z + v.w;
    float ss = v.x * v.x + v.y * v.y + v.z * v.z + v.w * v.w;
    #pragma unroll
    for (int o = 32; o; o >>= 1) { s += __shfl_down(s, o); ss += __shfl_down(ss, o); }
    __shared__ float red[4];
    if ((t & 63) == 0) { red[(t >> 6) * 2] = s; red[(t >> 6) * 2 + 1] = ss; }
    __syncthreads();
    s = red[0] + red[2]; ss = red[1] + red[3];
    const float mu = s * (1.f / D2);
    const float rstd = rsqrtf(ss * (1.f / D2) - mu * mu + 1e-5f);
    const float4 g4 = *(const float4*)(g + t * 4);
    const float4 b4 = *(const float4*)(bta + t * 4);
    const float hv[4] = {(v.x - mu) * rstd * g4.x + b4.x,
                         (v.y - mu) * rstd * g4.y + b4.y,
                         (v.z - mu) * rstd * g4.z + b4.z,
                         (v.w - mu) * rstd * g4.w + b4.w};
    float p[4] = {0, 0, 0, 0};
    #pragma unroll
    for (int i = 0; i < 4; ++i) {
        const float4 w = *(const float4*)(Wh + (size_t)(t * 4 + i) * NCLS);
        p[0] = fmaf(hv[i], w.x, p[0]); p[1] = fmaf(hv[i], w.y, p[1]);
        p[2] = fmaf(hv[i], w.z, p[2]); p[3] = fmaf(hv[i], w.w, p[3]);
    }
    #pragma unroll
    for (int o = 32; o; o >>= 1)
        #pragma unroll
        for (int c2 = 0; c2 < 4; ++c2) p[c2] += __shfl_down(p[c2], o);
    __shared__ float red2[2][4];
    if ((t & 63) == 0) {
        #pragma unroll
        for (int c2 = 0; c2 < 4; ++c2) red2[t >> 6][c2] = p[c2];
    }
    __syncthreads();
    if (t < 4) out[(size_t)row * NCLS + t] = red2[0][t] + red2[1][t] + bhd[t];
}

// ---------------------------------------------------------------------------
extern "C" void kernel_launch(void* const* d_in, const int* in_sizes, int n_in,
                              void* d_out, int out_size, void* d_ws, size_t ws_size,
                              hipStream_t stream) {
    const float* feature = (const float*)d_in[1];
    const int*   sp      = (const int*)d_in[2];
    const float* Wp      = (const float*)d_in[3];
    const float* bp      = (const float*)d_in[4];
    const float* ln1g    = (const float*)d_in[5];
    const float* ln1b    = (const float*)d_in[6];
    const float* Wqkv    = (const float*)d_in[7];
    const float* Wo      = (const float*)d_in[8];
    const float* bo      = (const float*)d_in[9];
    const float* ln2g    = (const float*)d_in[10];
    const float* ln2b    = (const float*)d_in[11];
    const float* W1      = (const float*)d_in[12];
    const float* b1      = (const float*)d_in[13];
    const float* W2      = (const float*)d_in[14];
    const float* b2      = (const float*)d_in[15];
    const float* lnfg    = (const float*)d_in[16];
    const float* lnfb    = (const float*)d_in[17];
    const float* Wh      = (const float*)d_in[18];
    const float* bhd     = (const float*)d_in[19];
    float* out = (float*)d_out;
    float* ws  = (float*)d_ws;

    // workspace layout (float slots, total 13,107,200 = 52.4 MB)
    float* x    = ws;                         // [2048*512]
    float* x0   = ws + 1048576;               // [2048*256]
    u16*   hlnH = (u16*)(ws + 1572864);       // [2048*512] bf16
    u16*   hlnL = hlnH + 1048576;
    u16*   h1H  = (u16*)(ws + 2621440);       // [2048*1024] bf16
    u16*   h1L  = h1H + 2097152;
    float* qkv  = ws + 4718592;               // q,k,v each [64,256,64] fp32
    float* sc   = ws + 7864320;               // [64,256,256] fp32 (also weight buf)
    u16*   wbuf = (u16*)sc;                   // transposed split weights (time-shared)
    u16*   oH   = (u16*)(ws + 12058624);      // [2048*512] bf16
    u16*   oL   = oH + 1048576;

    u16* qh = wbuf;                 // WqkvT hi  [1536][512]
    u16* ql = wbuf + 786432;        // WqkvT lo
    u16* woh = wbuf;                // WoT hi [512][512]   (after attention)
    u16* wol = wbuf + 262144;
    u16* w1h = wbuf + 524288;       // W1T hi [1024][512]
    u16* w1l = wbuf + 1048576;
    u16* w2h = wbuf + 1572864;      // W2T hi [512][1024]
    u16* w2l = wbuf + 2097152;

    k_init_x0<<<2048, 256, 0, stream>>>(x0, bp);
    k_patch<<<NPIX / PPB, 256, 0, stream>>>(feature, sp, Wp, x0);
    k_concat<<<dim3(NB, 16), 256, 0, stream>>>(x0, x);

    for (int d = 0; d < DEPTH; ++d) {
        k_cvtT<<<dim3(16, 48), 256, 0, stream>>>(Wqkv + (size_t)d * D2 * 3 * INNER,
                                                 qh, ql, D2, 3 * INNER);
        k_ln<<<NTOK, 128, 0, stream>>>(x, ln1g + d * D2, ln1b + d * D2, hlnH, hlnL);
        k_mfmm<512, 1536, 0><<<dim3(16, 12), 256, 0, stream>>>(
            hlnH, hlnL, qh, ql, nullptr, qkv, nullptr, nullptr);
        k_qk<<<dim3(4, 4, 64), 256, 0, stream>>>(qkv, qkv + 1048576, sc);
        k_softmax<<<4096, 256, 0, stream>>>(sc);
        k_pv<<<dim3(4, 1, 64), 256, 0, stream>>>(sc, qkv + 2097152, oH, oL);
        k_cvtT3<<<dim3(32, 32, 3), 256, 0, stream>>>(Wo + (size_t)d * INNER * D2,
                                                     W1 + (size_t)d * D2 * MLPD,
                                                     W2 + (size_t)d * MLPD * D2, wbuf);
        k_mfmm<512, 512, 1><<<dim3(16, 4), 256, 0, stream>>>(
            oH, oL, woh, wol, bo + d * D2, x, nullptr, nullptr);
        k_ln<<<NTOK, 128, 0, stream>>>(x, ln2g + d * D2, ln2b + d * D2, hlnH, hlnL);
        k_mfmm<512, 1024, 2><<<dim3(16, 8), 256, 0, stream>>>(
            hlnH, hlnL, w1h, w1l, b1 + d * MLPD, nullptr, h1H, h1L);
        k_mfmm<1024, 512, 1><<<dim3(16, 4), 256, 0, stream>>>(
            h1H, h1L, w2h, w2l, b2 + d * D2, x, nullptr, nullptr);
    }
    k_head<<<NTOK, 128, 0, stream>>>(x, lnfg, lnfb, Wh, bhd, out);
}

// Round 7
// 1097.759 us; speedup vs baseline: 1.3659x; 1.0051x over previous
//
#include <hip/hip_runtime.h>
#include <hip/hip_bf16.h>
#include <math.h>

// Problem constants
#define NB 8
#define NC 64
#define NS 64
#define NPIX 4096      // NS*NS
#define NSEG 256
#define DIM 256
#define DEPTH 4
#define HEADS 8
#define DHD 64
#define MLPD 1024
#define NCLS 4
#define D2 512
#define INNER 512
#define NTOK 2048      // NB*NSEG

typedef unsigned short u16;
typedef unsigned int u32;
typedef __attribute__((ext_vector_type(4))) float f32x4;
typedef __attribute__((ext_vector_type(8))) short short8;

// ---- fp32 -> (hi,lo) bf16 split, RNE --------------------------------------
__device__ __forceinline__ u16 bf16_rne(float x) {
    u32 u = __float_as_uint(x);
    return (u16)((u + 0x7FFFu + ((u >> 16) & 1u)) >> 16);
}
__device__ __forceinline__ void split2(float x, u16& h, u16& l) {
    h = bf16_rne(x);
    float hf = __uint_as_float((u32)h << 16);
    l = bf16_rne(x - hf);
}

// ---------------------------------------------------------------------------
// Patch embedding
// ---------------------------------------------------------------------------
__global__ __launch_bounds__(256) void k_init_x0(float* __restrict__ x0,
                                                 const float* __restrict__ bp) {
    int idx = blockIdx.x * 256 + threadIdx.x;
    x0[idx] = bp[idx & (DIM - 1)];
}

#define PPB 4
__global__ __launch_bounds__(256) void k_patch(const float* __restrict__ feature,
                                               const int* __restrict__ sp,
                                               const float* __restrict__ Wp,
                                               float* __restrict__ x0) {
    __shared__ __align__(16) float f[NB * NC][PPB];     // 8 KB
    __shared__ int seg[NB][PPB];
    const int p0 = blockIdx.x * PPB;
    const int t = threadIdx.x;
    const float* feat2 = feature + (size_t)2 * NB * NC * NPIX;
    #pragma unroll
    for (int i = 0; i < 2; ++i) {
        int pair = t + i * 256;            // b*64+c
        *(float4*)&f[pair][0] = *(const float4*)&feat2[(size_t)pair * NPIX + p0];
    }
    if (t < NB * PPB) seg[t >> 2][t & 3] = sp[(t >> 2) * NPIX + p0 + (t & 3)];
    __syncthreads();
    const int d = t;   // 0..255
    for (int q = 0; q < PPB; ++q) {
        float acc[NB];
        #pragma unroll
        for (int b = 0; b < NB; ++b) acc[b] = 0.f;
        const float* wcol = Wp + (size_t)(p0 + q) * DIM + d;
        #pragma unroll 8
        for (int c = 0; c < NC; ++c) {
            float w = wcol[(size_t)c * NPIX * DIM];   // 1 KB coalesced per (c,q)
            #pragma unroll
            for (int b = 0; b < NB; ++b) acc[b] = fmaf(f[b * NC + c][q], w, acc[b]);
        }
        #pragma unroll
        for (int b = 0; b < NB; ++b)
            atomicAdd(&x0[((b * NSEG) + seg[b][q]) * DIM + d], acc[b]);
    }
}

__global__ __launch_bounds__(256) void k_concat(const float* __restrict__ x0,
                                                float* __restrict__ x) {
    const int b = blockIdx.x, part = blockIdx.y;
    const int d = threadIdx.x;
    const float* xb = x0 + (size_t)b * NSEG * DIM;
    float g = -INFINITY;
    for (int s = 0; s < NSEG; ++s) g = fmaxf(g, xb[s * DIM + d]);
    for (int s = part * 16; s < part * 16 + 16; ++s) {
        float* row = x + ((size_t)(b * NSEG + s)) * D2;
        row[d] = g;
        row[DIM + d] = xb[s * DIM + d];
    }
}

// ---------------------------------------------------------------------------
// LayerNorm over 512 -> split bf16 (hi/lo) output
// ---------------------------------------------------------------------------
__global__ __launch_bounds__(128) void k_ln(const float* __restrict__ x,
                                            const float* __restrict__ g,
                                            const float* __restrict__ bta,
                                            u16* __restrict__ outH,
                                            u16* __restrict__ outL) {
    const int row = blockIdx.x, t = threadIdx.x;
    const float4 v = *(const float4*)(x + (size_t)row * D2 + t * 4);
    float s = v.x + v.y + v.z + v.w;
    float ss = v.x * v.x + v.y * v.y + v.z * v.z + v.w * v.w;
    #pragma unroll
    for (int o = 32; o; o >>= 1) { s += __shfl_down(s, o); ss += __shfl_down(ss, o); }
    __shared__ float red[4];
    if ((t & 63) == 0) { red[(t >> 6) * 2] = s; red[(t >> 6) * 2 + 1] = ss; }
    __syncthreads();
    s = red[0] + red[2]; ss = red[1] + red[3];
    const float mu = s * (1.f / D2);
    const float rstd = rsqrtf(ss * (1.f / D2) - mu * mu + 1e-5f);
    const float4 g4 = *(const float4*)(g + t * 4);
    const float4 b4 = *(const float4*)(bta + t * 4);
    float o4[4] = {(v.x - mu) * rstd * g4.x + b4.x,
                   (v.y - mu) * rstd * g4.y + b4.y,
                   (v.z - mu) * rstd * g4.z + b4.z,
                   (v.w - mu) * rstd * g4.w + b4.w};
    u16 h[4], l[4];
    #pragma unroll
    for (int i = 0; i < 4; ++i) split2(o4[i], h[i], l[i]);
    *(ushort4*)(outH + (size_t)row * D2 + t * 4) = make_ushort4(h[0], h[1], h[2], h[3]);
    *(ushort4*)(outL + (size_t)row * D2 + t * 4) = make_ushort4(l[0], l[1], l[2], l[3]);
}

// ---------------------------------------------------------------------------
// Weight transpose + split:  src fp32 [K][N] -> dstH/dstL bf16 [N][K]
// ---------------------------------------------------------------------------
__device__ __forceinline__ void cvt_tile(const float* __restrict__ src, int K, int N,
                                         u16* __restrict__ dH, u16* __restrict__ dL,
                                         int k0, int n0) {
    __shared__ __align__(16) float ls[32][33];
    const int t = threadIdx.x;
    const int r = t >> 3, cg = t & 7;
    const float4 v = *(const float4*)(src + (size_t)(k0 + r) * N + n0 + cg * 4);
    ls[r][cg * 4 + 0] = v.x; ls[r][cg * 4 + 1] = v.y;
    ls[r][cg * 4 + 2] = v.z; ls[r][cg * 4 + 3] = v.w;
    __syncthreads();
    u16 h[4], l[4];
    #pragma unroll
    for (int i = 0; i < 4; ++i) split2(ls[cg * 4 + i][r], h[i], l[i]);
    *(ushort4*)(dH + (size_t)(n0 + r) * K + k0 + cg * 4) = make_ushort4(h[0], h[1], h[2], h[3]);
    *(ushort4*)(dL + (size_t)(n0 + r) * K + k0 + cg * 4) = make_ushort4(l[0], l[1], l[2], l[3]);
}

__global__ __launch_bounds__(256) void k_cvtT(const float* __restrict__ src,
                                              u16* __restrict__ dH, u16* __restrict__ dL,
                                              int K, int N) {
    cvt_tile(src, K, N, dH, dL, blockIdx.x * 32, blockIdx.y * 32);
}

__global__ __launch_bounds__(256) void k_cvtT3(const float* __restrict__ sO,
                                               const float* __restrict__ s1,
                                               const float* __restrict__ s2,
                                               u16* __restrict__ wb) {
    int K, N; const float* src; u16 *dH, *dL;
    if (blockIdx.z == 0)      { K = 512;  N = 512;  src = sO; dH = wb;           dL = wb + 262144; }
    else if (blockIdx.z == 1) { K = 512;  N = 1024; src = s1; dH = wb + 524288;  dL = wb + 1048576; }
    else                      { K = 1024; N = 512;  src = s2; dH = wb + 1572864; dL = wb + 2097152; }
    const int k0 = blockIdx.x * 32, n0 = blockIdx.y * 32;
    if (k0 >= K || n0 >= N) return;
    cvt_tile(src, K, N, dH, dL, k0, n0);
}

// ---------------------------------------------------------------------------
// Split-bf16 MFMA GEMM: C[M,NN] = (Ah+Al)[M,K] @ (Bh+Bl)^T[NN,K]
// 128x128 block tile, BK=32, 4 waves (2x2), wave tile 64x64 (4x4 frags 16x16x32)
// MODE 0: split-bf16 scatter to qkvS (q/k row-major, v transposed);
// MODE 1: X += acc + bias; MODE 2: gelu -> split bf16
// ---------------------------------------------------------------------------
template<int K, int NN, int MODE>
__global__ __launch_bounds__(256) void k_mfmm(const u16* __restrict__ Ah,
                                              const u16* __restrict__ Al,
                                              const u16* __restrict__ Bh,
                                              const u16* __restrict__ Bl,
                                              const float* __restrict__ bias,
                                              float* __restrict__ Cf,
                                              u16* __restrict__ CoH,
                                              u16* __restrict__ CoL) {
    __shared__ __align__(16) u16 AsH[128][40], AsL[128][40], BsH[128][40], BsL[128][40];  // 40 KB
    const int m0 = blockIdx.x * 128, n0 = blockIdx.y * 128;
    const int t = threadIdx.x;
    const int srow = t >> 1, soff = (t & 1) * 16;   // 2 thr/row, 16 bf16 each
    const int lane = t & 63;
    const int wr = (t >> 7) & 1, wc = (t >> 6) & 1;
    const int lrow = lane & 15, lk = lane >> 4;

    const u16* pAh = Ah + (size_t)(m0 + srow) * K + soff;
    const u16* pAl = Al + (size_t)(m0 + srow) * K + soff;
    const u16* pBh = Bh + (size_t)(n0 + srow) * K + soff;
    const u16* pBl = Bl + (size_t)(n0 + srow) * K + soff;

    uint4 rAh0 = *(const uint4*)pAh,       rAh1 = *(const uint4*)(pAh + 8);
    uint4 rAl0 = *(const uint4*)pAl,       rAl1 = *(const uint4*)(pAl + 8);
    uint4 rBh0 = *(const uint4*)pBh,       rBh1 = *(const uint4*)(pBh + 8);
    uint4 rBl0 = *(const uint4*)pBl,       rBl1 = *(const uint4*)(pBl + 8);

    f32x4 acc[4][4];
    #pragma unroll
    for (int i = 0; i < 4; ++i)
        #pragma unroll
        for (int j = 0; j < 4; ++j) acc[i][j] = (f32x4){0.f, 0.f, 0.f, 0.f};

    #pragma unroll 1
    for (int k0 = 0; k0 < K; k0 += 32) {
        __syncthreads();
        *(uint4*)&AsH[srow][soff] = rAh0;  *(uint4*)&AsH[srow][soff + 8] = rAh1;
        *(uint4*)&AsL[srow][soff] = rAl0;  *(uint4*)&AsL[srow][soff + 8] = rAl1;
        *(uint4*)&BsH[srow][soff] = rBh0;  *(uint4*)&BsH[srow][soff + 8] = rBh1;
        *(uint4*)&BsL[srow][soff] = rBl0;  *(uint4*)&BsL[srow][soff + 8] = rBl1;
        __syncthreads();
        if (k0 + 32 < K) {
            rAh0 = *(const uint4*)(pAh + k0 + 32);  rAh1 = *(const uint4*)(pAh + k0 + 40);
            rAl0 = *(const uint4*)(pAl + k0 + 32);  rAl1 = *(const uint4*)(pAl + k0 + 40);
            rBh0 = *(const uint4*)(pBh + k0 + 32);  rBh1 = *(const uint4*)(pBh + k0 + 40);
            rBl0 = *(const uint4*)(pBl + k0 + 32);  rBl1 = *(const uint4*)(pBl + k0 + 40);
        }
        short8 ah[4], al[4], bh[4], bl[4];
        #pragma unroll
        for (int i = 0; i < 4; ++i) {
            ah[i] = *(const short8*)&AsH[wr * 64 + i * 16 + lrow][lk * 8];
            al[i] = *(const short8*)&AsL[wr * 64 + i * 16 + lrow][lk * 8];
            bh[i] = *(const short8*)&BsH[wc * 64 + i * 16 + lrow][lk * 8];
            bl[i] = *(const short8*)&BsL[wc * 64 + i * 16 + lrow][lk * 8];
        }
        #pragma unroll
        for (int i = 0; i < 4; ++i)
            #pragma unroll
            for (int j = 0; j < 4; ++j) {
                acc[i][j] = __builtin_amdgcn_mfma_f32_16x16x32_bf16(ah[i], bh[j], acc[i][j], 0, 0, 0);
                acc[i][j] = __builtin_amdgcn_mfma_f32_16x16x32_bf16(ah[i], bl[j], acc[i][j], 0, 0, 0);
                acc[i][j] = __builtin_amdgcn_mfma_f32_16x16x32_bf16(al[i], bh[j], acc[i][j], 0, 0, 0);
            }
    }
    // epilogue: D frag layout col=lane&15, row=(lane>>4)*4+reg   [m89/m91]
    #pragma unroll
    for (int i = 0; i < 4; ++i) {
        #pragma unroll
        for (int j = 0; j < 4; ++j) {
            #pragma unroll
            for (int r = 0; r < 4; ++r) {
                const int row = m0 + wr * 64 + i * 16 + lk * 4 + r;
                const int col = n0 + wc * 64 + j * 16 + lrow;
                float v = acc[i][j][r];
                if (MODE == 0) {
                    // CoH = qkvS base: qH|qL|kH|kL|vTH|vTL, each 1048576 u16
                    const int which = col >> 9, hd = (col >> 6) & 7, dh = col & 63;
                    const int b = row >> 8, nn = row & 255;
                    u16 h, l; split2(v, h, l);
                    size_t off;
                    if (which == 2)
                        off = (size_t)4194304 + ((size_t)((b * 8 + hd) * 64 + dh)) * 256 + nn;
                    else
                        off = (size_t)which * 2097152 + ((size_t)((b * 8 + hd) * 256 + nn)) * 64 + dh;
                    CoH[off] = h; CoH[off + 1048576] = l;
                } else if (MODE == 1) {
                    float* xp = Cf + (size_t)row * NN + col;
                    *xp += v + bias[col];
                } else {
                    v += bias[col];
                    float gl = 0.5f * v * (1.f + erff(v * 0.70710678118654752f));
                    u16 h, l; split2(gl, h, l);
                    CoH[(size_t)row * NN + col] = h;
                    CoL[(size_t)row * NN + col] = l;
                }
            }
        }
    }
}

// ---------------------------------------------------------------------------
// Fused MFMA attention: per block = 64 q-rows x one (b,h); 4 waves x 16 rows.
// QK^T (split bf16, 3-term) -> in-reg softmax -> E to LDS -> PV -> normalize.
// qkvS: qH|qL|kH|kL (row-major [bh][n][d]), vTH|vTL ([bh][d][n]); 1048576 u16 each.
// ---------------------------------------------------------------------------
__global__ __launch_bounds__(256) void k_attn(const u16* __restrict__ qkvS,
                                              u16* __restrict__ oH,
                                              u16* __restrict__ oL) {
    __shared__ __align__(16) u16 Ph[4][16][264], Pl[4][16][264];   // 67.6 KB, pad 16B
    const int bh = blockIdx.y;
    const int w = threadIdx.x >> 6, lane = threadIdx.x & 63;
    const int row = lane & 15, hi = lane >> 4;
    const int r0 = blockIdx.x * 64 + w * 16;

    const u16* qHp = qkvS;
    const u16* qLp = qkvS + 1048576;
    const u16* kHp = qkvS + 2097152;
    const u16* kLp = qkvS + 3145728;
    const u16* vHp = qkvS + 4194304;
    const u16* vLp = qkvS + 5242880;

    // Q A-frags (row=lane&15, k=8*hi+j), 2 k-steps of 32
    short8 qh[2], ql[2];
    #pragma unroll
    for (int ks = 0; ks < 2; ++ks) {
        const size_t a = ((size_t)bh * 256 + r0 + row) * 64 + ks * 32 + hi * 8;
        qh[ks] = *(const short8*)(qHp + a);
        ql[ks] = *(const short8*)(qLp + a);
    }

    // scores: 16 key-frags of 16 cols
    f32x4 sacc[16];
    #pragma unroll
    for (int j = 0; j < 16; ++j) sacc[j] = (f32x4){0.f, 0.f, 0.f, 0.f};
    #pragma unroll
    for (int j = 0; j < 16; ++j) {
        #pragma unroll
        for (int ks = 0; ks < 2; ++ks) {
            const size_t a = ((size_t)bh * 256 + j * 16 + row) * 64 + ks * 32 + hi * 8;
            short8 kh = *(const short8*)(kHp + a);
            short8 kl = *(const short8*)(kLp + a);
            sacc[j] = __builtin_amdgcn_mfma_f32_16x16x32_bf16(qh[ks], kh, sacc[j], 0, 0, 0);
            sacc[j] = __builtin_amdgcn_mfma_f32_16x16x32_bf16(qh[ks], kl, sacc[j], 0, 0, 0);
            sacc[j] = __builtin_amdgcn_mfma_f32_16x16x32_bf16(ql[ks], kh, sacc[j], 0, 0, 0);
        }
    }

    // softmax over 256 cols; C-layout row = 4*hi + r, col = lane&15 + 16j.
    // Lanes sharing hi (16-lane group) hold the same rows -> shfl_xor<16 reduce.
    float rsum[4];
    #pragma unroll
    for (int r = 0; r < 4; ++r) {
        float m = sacc[0][r];
        #pragma unroll
        for (int j = 1; j < 16; ++j) m = fmaxf(m, sacc[j][r]);
        #pragma unroll
        for (int o = 1; o < 16; o <<= 1) m = fmaxf(m, __shfl_xor(m, o));
        float s = 0.f;
        #pragma unroll
        for (int j = 0; j < 16; ++j) {
            float e = __expf((sacc[j][r] - m) * 0.125f);
            sacc[j][r] = e;
            s += e;
        }
        #pragma unroll
        for (int o = 1; o < 16; o <<= 1) s += __shfl_xor(s, o);
        rsum[r] = 1.f / s;
    }

    // E -> LDS (split bf16), [w][row][col]
    #pragma unroll
    for (int j = 0; j < 16; ++j) {
        #pragma unroll
        for (int r = 0; r < 4; ++r) {
            u16 h, l; split2(sacc[j][r], h, l);
            Ph[w][4 * hi + r][row + 16 * j] = h;
            Pl[w][4 * hi + r][row + 16 * j] = l;
        }
    }
    __syncthreads();

    // PV: O[16 rows][64 d] = E @ V ; A from LDS, B = vT (n=d=lane&15, k contiguous)
    f32x4 oacc[4];
    #pragma unroll
    for (int df = 0; df < 4; ++df) oacc[df] = (f32x4){0.f, 0.f, 0.f, 0.f};
    #pragma unroll
    for (int ks = 0; ks < 8; ++ks) {
        short8 pah = *(const short8*)&Ph[w][row][ks * 32 + hi * 8];
        short8 pal = *(const short8*)&Pl[w][row][ks * 32 + hi * 8];
        #pragma unroll
        for (int df = 0; df < 4; ++df) {
            const size_t a = ((size_t)bh * 64 + df * 16 + row) * 256 + ks * 32 + hi * 8;
            short8 vh = *(const short8*)(vHp + a);
            short8 vl = *(const short8*)(vLp + a);
            oacc[df] = __builtin_amdgcn_mfma_f32_16x16x32_bf16(pah, vh, oacc[df], 0, 0, 0);
            oacc[df] = __builtin_amdgcn_mfma_f32_16x16x32_bf16(pah, vl, oacc[df], 0, 0, 0);
            oacc[df] = __builtin_amdgcn_mfma_f32_16x16x32_bf16(pal, vh, oacc[df], 0, 0, 0);
        }
    }

    // normalize + write o[(b*256+n)*512 + h*64 + d] split bf16
    const int b = bh >> 3, hd = bh & 7;
    #pragma unroll
    for (int df = 0; df < 4; ++df) {
        #pragma unroll
        for (int r = 0; r < 4; ++r) {
            float v = oacc[df][r] * rsum[r];
            u16 h, l; split2(v, h, l);
            const int n = r0 + 4 * hi + r;
            const size_t idx = ((size_t)(b * 256 + n)) * 512 + hd * 64 + df * 16 + row;
            oH[idx] = h; oL[idx] = l;
        }
    }
}

__global__ __launch_bounds__(128) void k_head(const float* __restrict__ x,
                                              const float* __restrict__ g,
                                              const float* __restrict__ bta,
                                              const float* __restrict__ Wh,
                                              const float* __restrict__ bhd,
                                              float* __restrict__ out) {
    const int row = blockIdx.x, t = threadIdx.x;
    const float4 v = *(const float4*)(x + (size_t)row * D2 + t * 4);
    float s = v.x + v.y + v.z + v.w;
    float ss = v.x * v.x + v.y * v.y + v.z * v.z + v.w * v.w;
    #pragma unroll
    for (int o = 32; o; o >>= 1) { s += __shfl_down(s, o); ss += __shfl_down(ss, o); }
    __shared__ float red[4];
    if ((t & 63) == 0) { red[(t >> 6) * 2] = s; red[(t >> 6) * 2 + 1] = ss; }
    __syncthreads();
    s = red[0] + red[2]; ss = red[1] + red[3];
    const float mu = s * (1.f / D2);
    const float rstd = rsqrtf(ss * (1.f / D2) - mu * mu + 1e-5f);
    const float4 g4 = *(const float4*)(g + t * 4);
    const float4 b4 = *(const float4*)(bta + t * 4);
    const float hv[4] = {(v.x - mu) * rstd * g4.x + b4.x,
                         (v.y - mu) * rstd * g4.y + b4.y,
                         (v.z - mu) * rstd * g4.z + b4.z,
                         (v.w - mu) * rstd * g4.w + b4.w};
    float p[4] = {0, 0, 0, 0};
    #pragma unroll
    for (int i = 0; i < 4; ++i) {
        const float4 w = *(const float4*)(Wh + (size_t)(t * 4 + i) * NCLS);
        p[0] = fmaf(hv[i], w.x, p[0]); p[1] = fmaf(hv[i], w.y, p[1]);
        p[2] = fmaf(hv[i], w.z, p[2]); p[3] = fmaf(hv[i], w.w, p[3]);
    }
    #pragma unroll
    for (int o = 32; o; o >>= 1)
        #pragma unroll
        for (int c2 = 0; c2 < 4; ++c2) p[c2] += __shfl_down(p[c2], o);
    __shared__ float red2[2][4];
    if ((t & 63) == 0) {
        #pragma unroll
        for (int c2 = 0; c2 < 4; ++c2) red2[t >> 6][c2] = p[c2];
    }
    __syncthreads();
    if (t < 4) out[(size_t)row * NCLS + t] = red2[0][t] + red2[1][t] + bhd[t];
}

// ---------------------------------------------------------------------------
extern "C" void kernel_launch(void* const* d_in, const int* in_sizes, int n_in,
                              void* d_out, int out_size, void* d_ws, size_t ws_size,
                              hipStream_t stream) {
    const float* feature = (const float*)d_in[1];
    const int*   sp      = (const int*)d_in[2];
    const float* Wp      = (const float*)d_in[3];
    const float* bp      = (const float*)d_in[4];
    const float* ln1g    = (const float*)d_in[5];
    const float* ln1b    = (const float*)d_in[6];
    const float* Wqkv    = (const float*)d_in[7];
    const float* Wo      = (const float*)d_in[8];
    const float* bo      = (const float*)d_in[9];
    const float* ln2g    = (const float*)d_in[10];
    const float* ln2b    = (const float*)d_in[11];
    const float* W1      = (const float*)d_in[12];
    const float* b1      = (const float*)d_in[13];
    const float* W2      = (const float*)d_in[14];
    const float* b2      = (const float*)d_in[15];
    const float* lnfg    = (const float*)d_in[16];
    const float* lnfb    = (const float*)d_in[17];
    const float* Wh      = (const float*)d_in[18];
    const float* bhd     = (const float*)d_in[19];
    float* out = (float*)d_out;
    float* ws  = (float*)d_ws;

    // workspace layout (float slots, total 13,107,200 = 52.4 MB)
    float* x    = ws;                         // [2048*512]
    float* x0   = ws + 1048576;               // [2048*256]
    u16*   hlnH = (u16*)(ws + 1572864);       // [2048*512] bf16
    u16*   hlnL = hlnH + 1048576;
    u16*   h1H  = (u16*)(ws + 2621440);       // [2048*1024] bf16
    u16*   h1L  = h1H + 2097152;
    u16*   qkvS = (u16*)(ws + 4718592);       // qH|qL|kH|kL|vTH|vTL, 1048576 u16 each
    float* sc   = ws + 7864320;               // weight buf region
    u16*   wbuf = (u16*)sc;                   // transposed split weights (time-shared)
    u16*   oH   = (u16*)(ws + 12058624);      // [2048*512] bf16
    u16*   oL   = oH + 1048576;

    u16* qh = wbuf;                 // WqkvT hi  [1536][512]
    u16* ql = wbuf + 786432;        // WqkvT lo
    u16* woh = wbuf;                // WoT hi [512][512]   (after attention)
    u16* wol = wbuf + 262144;
    u16* w1h = wbuf + 524288;       // W1T hi [1024][512]
    u16* w1l = wbuf + 1048576;
    u16* w2h = wbuf + 1572864;      // W2T hi [512][1024]
    u16* w2l = wbuf + 2097152;

    k_init_x0<<<2048, 256, 0, stream>>>(x0, bp);
    k_patch<<<NPIX / PPB, 256, 0, stream>>>(feature, sp, Wp, x0);
    k_concat<<<dim3(NB, 16), 256, 0, stream>>>(x0, x);

    for (int d = 0; d < DEPTH; ++d) {
        k_cvtT<<<dim3(16, 48), 256, 0, stream>>>(Wqkv + (size_t)d * D2 * 3 * INNER,
                                                 qh, ql, D2, 3 * INNER);
        k_ln<<<NTOK, 128, 0, stream>>>(x, ln1g + d * D2, ln1b + d * D2, hlnH, hlnL);
        k_mfmm<512, 1536, 0><<<dim3(16, 12), 256, 0, stream>>>(
            hlnH, hlnL, qh, ql, nullptr, nullptr, qkvS, nullptr);
        k_attn<<<dim3(4, 64), 256, 0, stream>>>(qkvS, oH, oL);
        k_cvtT3<<<dim3(32, 32, 3), 256, 0, stream>>>(Wo + (size_t)d * INNER * D2,
                                                     W1 + (size_t)d * D2 * MLPD,
                                                     W2 + (size_t)d * MLPD * D2, wbuf);
        k_mfmm<512, 512, 1><<<dim3(16, 4), 256, 0, stream>>>(
            oH, oL, woh, wol, bo + d * D2, x, nullptr, nullptr);
        k_ln<<<NTOK, 128, 0, stream>>>(x, ln2g + d * D2, ln2b + d * D2, hlnH, hlnL);
        k_mfmm<512, 1024, 2><<<dim3(16, 8), 256, 0, stream>>>(
            hlnH, hlnL, w1h, w1l, b1 + d * MLPD, nullptr, h1H, h1L);
        k_mfmm<1024, 512, 1><<<dim3(16, 4), 256, 0, stream>>>(
            h1H, h1L, w2h, w2l, b2 + d * D2, x, nullptr, nullptr);
    }
    k_head<<<NTOK, 128, 0, stream>>>(x, lnfg, lnfb, Wh, bhd, out);
}